// Round 8
// baseline (7433.493 us; speedup 1.0000x reference)
//
#include <hip/hip_runtime.h>
#include <hip/hip_bf16.h>

#define TDIM 1024
#define HDIM 1024
#define IDIM 1024
#define BSZ  64

typedef __attribute__((ext_vector_type(4))) float  floatx4;
typedef __attribute__((ext_vector_type(2))) float  floatx2;
typedef __attribute__((ext_vector_type(8))) short  shortx8;

static __device__ __forceinline__ short f2bf(float x) {
    unsigned u = __builtin_bit_cast(unsigned, x);
    u += 0x7fffu + ((u >> 16) & 1u);           // round-to-nearest-even
    return (short)(u >> 16);
}

static __device__ __forceinline__ shortx8 pack8(floatx4 a, floatx4 b) {
    shortx8 r;
    r[0] = f2bf(a[0]); r[1] = f2bf(a[1]); r[2] = f2bf(a[2]); r[3] = f2bf(a[3]);
    r[4] = f2bf(b[0]); r[5] = f2bf(b[1]); r[6] = f2bf(b[2]); r[7] = f2bf(b[3]);
    return r;
}

// MALL-scope primitives (round-4 lesson: cross-WG exchange MUST be sc0+sc1).
static __device__ __forceinline__ unsigned long long ld_mall8(const unsigned* p) {
    unsigned long long v;
    asm volatile("global_load_dwordx2 %0, %1, off sc0 sc1"
                 : "=v"(v) : "v"(p) : "memory");
    return v;
}
static __device__ __forceinline__ void st_tag(unsigned* p, unsigned v) {
    asm volatile("global_store_dword %0, %1, off sc0 sc1" :: "v"(p), "v"(v) : "memory");
}

// Swizzled LDS byte offset: pitch 1024 shorts (2048 B), XOR (row&7)<<4.
// Conflict-free for both the staging writes (lane-consecutive banks) and the
// MFMA b128 reads (each consecutive-8-lane block hits 8 distinct bank groups).
#define SWZ(row, bytecol) ((((row) * 2048) + (bytecol)) ^ (((row) & 7) << 4))

// ---------------------------------------------------------------------------
// Phase A: out[m][n] = sum_k input[m][k] * W_ih[n][k] + b_ih[n] + b_hh[n]
// (unchanged — ~0.75 ms)
// ---------------------------------------------------------------------------
__global__ __launch_bounds__(256, 2)
void xp_gemm(const float* __restrict__ A, const float* __restrict__ W,
             const float* __restrict__ bih, const float* __restrict__ bhh,
             float* __restrict__ out)
{
    __shared__ short As[128 * 72];
    __shared__ short Bs[128 * 72];

    const int tid  = threadIdx.x;
    const int bx   = blockIdx.x;
    const int m0   = (bx >> 3) * 128;
    const int n0   = (bx & 7) * 128;
    const int lane = tid & 63;
    const int w    = tid >> 6;
    const int wm   = w & 1, wn = w >> 1;
    const int col  = lane & 15, quad = lane >> 4;

    const int srow = tid >> 1;
    const int scol = (tid & 1) * 32;
    const float* ap = A + (size_t)(m0 + srow) * IDIM + scol;
    const float* wp = W + (size_t)(n0 + srow) * IDIM + scol;
    short* asw = As + srow * 72 + scol;
    short* bsw = Bs + srow * 72 + scol;

    floatx4 acc[4][4];
#pragma unroll
    for (int i = 0; i < 4; i++)
#pragma unroll
        for (int j = 0; j < 4; j++) acc[i][j] = (floatx4){0.f, 0.f, 0.f, 0.f};

    for (int kt = 0; kt < IDIM; kt += 64) {
        floatx4 av[8], bv[8];
        const floatx4* pa = (const floatx4*)(ap + kt);
        const floatx4* pb = (const floatx4*)(wp + kt);
#pragma unroll
        for (int q = 0; q < 8; q++) { av[q] = pa[q]; bv[q] = pb[q]; }
        __syncthreads();
#pragma unroll
        for (int q = 0; q < 4; q++) {
            *(shortx8*)(asw + q * 8) = pack8(av[2 * q], av[2 * q + 1]);
            *(shortx8*)(bsw + q * 8) = pack8(bv[2 * q], bv[2 * q + 1]);
        }
        __syncthreads();
#pragma unroll
        for (int kb = 0; kb < 64; kb += 32) {
            shortx8 af[4], bf[4];
#pragma unroll
            for (int i = 0; i < 4; i++)
                af[i] = *(const shortx8*)(As + (wm * 64 + i * 16 + col) * 72 + kb + quad * 8);
#pragma unroll
            for (int j = 0; j < 4; j++)
                bf[j] = *(const shortx8*)(Bs + (wn * 64 + j * 16 + col) * 72 + kb + quad * 8);
#pragma unroll
            for (int i = 0; i < 4; i++)
#pragma unroll
                for (int j = 0; j < 4; j++)
                    acc[i][j] = __builtin_amdgcn_mfma_f32_16x16x32_bf16(af[i], bf[j], acc[i][j], 0, 0, 0);
        }
    }

#pragma unroll
    for (int j = 0; j < 4; j++) {
        const int n = n0 + wn * 64 + j * 16 + col;
        const float bias = bih[n] + bhh[n];
#pragma unroll
        for (int i = 0; i < 4; i++) {
            const int mb = m0 + wm * 64 + i * 16 + quad * 4;
#pragma unroll
            for (int r = 0; r < 4; r++)
                out[(size_t)(mb + r) * HDIM + n] = acc[i][j][r] + bias;
        }
    }
}

// ---------------------------------------------------------------------------
// Phase B: recurrence, dual-chain latency hiding.
// 32 WGs x 512 thr = 4 pairs x 8 roles.  Pair p owns chains:
//   A = batches p*16..p*16+7   (exchange group 2p)
//   B = batches p*16+8..+15    (exchange group 2p+1)
// Each iteration runs phase(A) then phase(B).  A phase computes chain X and
// does the exchange wait for chain Y — Y's poll loads are issued mid-MFMA_X
// (~700cy after Y's producers published) and validated after X's tanh+
// publish, so the MALL RTT hides under real compute and retries ~vanish.
// Exchange: tag-in-word (bf16<<16 | step), sc1 stores, no acks.
// vmcnt choreography per phase (all register-tied, no compiler drains):
//   polls(8) ... vmcnt(20) [xp ready, polls kept] ... publish(4)+out(4)+
//   prefetch(4) ... vmcnt(12) [exactly the polls retired] ... stage ... bar.
// Slot safety (depth 2): my publish X(t+1) is gated through my stage of
// X(t) <= ALL peers published X(t) <= each peer validated X(t-1), i.e. its
// slot-(t+1)&1 reads retired.  Correctness never depends on timing.
// ---------------------------------------------------------------------------
static __device__ __forceinline__ void phase(
    const short* ldsX, short* ldsY, const shortx8* bfrag, float* xp,
    float* __restrict__ out, unsigned* __restrict__ hexch,
    int t, int ts, int batX, int grpX, int grpY,
    int nglob, int b0, int bsafe, int col, int quad, int w, int lane)
{
    floatx4 a0 = (floatx4){0.f, 0.f, 0.f, 0.f};
    floatx4 a1 = a0, a2 = a0, a3 = a0;
    const char* lb = (const char*)ldsX;
    const int rb = col * 2048;
    const int sx = (col & 7) << 4;

#pragma unroll
    for (int kb = 0; kb < 16; kb += 4) {
        shortx8 f0 = *(const shortx8*)(lb + ((rb + (kb + 0) * 64 + quad * 16) ^ sx));
        shortx8 f1 = *(const shortx8*)(lb + ((rb + (kb + 1) * 64 + quad * 16) ^ sx));
        shortx8 f2 = *(const shortx8*)(lb + ((rb + (kb + 2) * 64 + quad * 16) ^ sx));
        shortx8 f3 = *(const shortx8*)(lb + ((rb + (kb + 3) * 64 + quad * 16) ^ sx));
        a0 = __builtin_amdgcn_mfma_f32_16x16x32_bf16(f0, bfrag[kb + 0], a0, 0, 0, 0);
        a1 = __builtin_amdgcn_mfma_f32_16x16x32_bf16(f1, bfrag[kb + 1], a1, 0, 0, 0);
        a2 = __builtin_amdgcn_mfma_f32_16x16x32_bf16(f2, bfrag[kb + 2], a2, 0, 0, 0);
        a3 = __builtin_amdgcn_mfma_f32_16x16x32_bf16(f3, bfrag[kb + 3], a3, 0, 0, 0);
    }

    // issue chain-Y poll loads mid-MFMA (producers published ~a phase ago)
    unsigned long long hv[8];
    const unsigned* psrc = hexch;
    if (ts >= 0) {
        psrc = hexch + ((unsigned)(ts & 1) << 16) + grpY * 8192 + (w * 128 + lane * 2);
        __builtin_amdgcn_sched_barrier(0);
#pragma unroll
        for (int j = 0; j < 8; j++) hv[j] = ld_mall8(psrc + (size_t)j * 1024);
        __builtin_amdgcn_sched_barrier(0);
    }

#pragma unroll
    for (int kb = 16; kb < 32; kb += 4) {
        shortx8 f0 = *(const shortx8*)(lb + ((rb + (kb + 0) * 64 + quad * 16) ^ sx));
        shortx8 f1 = *(const shortx8*)(lb + ((rb + (kb + 1) * 64 + quad * 16) ^ sx));
        shortx8 f2 = *(const shortx8*)(lb + ((rb + (kb + 2) * 64 + quad * 16) ^ sx));
        shortx8 f3 = *(const shortx8*)(lb + ((rb + (kb + 3) * 64 + quad * 16) ^ sx));
        a0 = __builtin_amdgcn_mfma_f32_16x16x32_bf16(f0, bfrag[kb + 0], a0, 0, 0, 0);
        a1 = __builtin_amdgcn_mfma_f32_16x16x32_bf16(f1, bfrag[kb + 1], a1, 0, 0, 0);
        a2 = __builtin_amdgcn_mfma_f32_16x16x32_bf16(f2, bfrag[kb + 2], a2, 0, 0, 0);
        a3 = __builtin_amdgcn_mfma_f32_16x16x32_bf16(f3, bfrag[kb + 3], a3, 0, 0, 0);
    }
    floatx4 acc = (a0 + a1) + (a2 + a3);

    // xp guaranteed retired (it has >=28 younger ops; ties prevent hoisting)
    if (ts >= 0)
        asm volatile("s_waitcnt vmcnt(20)"
                     : "+v"(xp[0]), "+v"(xp[1]), "+v"(xp[2]), "+v"(xp[3]) :: "memory");
    else
        asm volatile("s_waitcnt vmcnt(0)"
                     : "+v"(xp[0]), "+v"(xp[1]), "+v"(xp[2]), "+v"(xp[3]) :: "memory");
    __builtin_amdgcn_sched_barrier(0);

    float hval[4];
#pragma unroll
    for (int r = 0; r < 4; r++) hval[r] = tanhf(xp[r] + acc[r]);

    // publish X(t+1): tagged sc1 stores, fire-and-forget
    if (t + 1 < TDIM && b0 < 8) {
        unsigned* hd = hexch + ((unsigned)((t + 1) & 1) << 16) + grpX * 8192;
        const unsigned tag = (unsigned)(t + 1);
#pragma unroll
        for (int r = 0; r < 4; r++)
            st_tag(hd + (size_t)(b0 + r) * 1024 + nglob,
                   ((unsigned)(unsigned short)f2bf(hval[r]) << 16) | tag);
    }
    // WG-private output writes
    if (b0 < 8) {
#pragma unroll
        for (int r = 0; r < 4; r++) {
            const int b = batX + b0 + r;
            out[(size_t)b * (TDIM * HDIM) + (size_t)t * HDIM + nglob] = hval[r];
            if (t == TDIM - 1)
                out[(size_t)BSZ * TDIM * HDIM + (size_t)b * HDIM + nglob] = hval[r];
        }
    }
    // prefetch xp for X's next step (asm: no compiler-inserted drains)
    if (t + 1 < TDIM) {
#pragma unroll
        for (int r = 0; r < 4; r++) {
            const float* pf = out + (size_t)(batX + bsafe + r) * (TDIM * HDIM)
                                  + (size_t)(t + 1) * HDIM + nglob;
            asm volatile("global_load_dword %0, %1, off" : "=v"(xp[r]) : "v"(pf));
        }
    }

    // wait polls (exactly 12 younger ops), validate, stage Y -> LDS_Y
    if (ts >= 0) {
        asm volatile("s_waitcnt vmcnt(12)"
                     : "+v"(hv[0]), "+v"(hv[1]), "+v"(hv[2]), "+v"(hv[3]),
                       "+v"(hv[4]), "+v"(hv[5]), "+v"(hv[6]), "+v"(hv[7]) :: "memory");
        __builtin_amdgcn_sched_barrier(0);
        const unsigned long long msk = 0x0000FFFF0000FFFFULL;
        const unsigned long long tt  = (unsigned long long)(unsigned)ts;
        const unsigned long long pat = tt | (tt << 32);
        bool bad = false;
#pragma unroll
        for (int j = 0; j < 8; j++) bad |= ((hv[j] & msk) != pat);
        int guard = 0;
        while (__any((int)bad)) {
            if (++guard > (1 << 13)) break;      // fail-fast fuse (bounded)
            asm volatile("s_sleep 1");
#pragma unroll
            for (int j = 0; j < 8; j++) hv[j] = ld_mall8(psrc + (size_t)j * 1024);
            asm volatile("s_waitcnt vmcnt(0)" ::: "memory");
            __builtin_amdgcn_sched_barrier(0);
            bad = false;
#pragma unroll
            for (int j = 0; j < 8; j++) bad |= ((hv[j] & msk) != pat);
        }
        const int ccb = (w * 128 + lane * 2) * 2;   // byte col
#pragma unroll
        for (int j = 0; j < 8; j++) {
            const unsigned pk = (unsigned)((hv[j] >> 16) & 0xFFFFu) |
                                (unsigned)((hv[j] >> 32) & 0xFFFF0000u);
            *(unsigned*)((char*)ldsY + SWZ(j, ccb)) = pk;
        }
    }
    asm volatile("s_waitcnt lgkmcnt(0)" ::: "memory");
    __builtin_amdgcn_s_barrier();
}

__global__ __launch_bounds__(512, 1)
void rnn_rec(float* __restrict__ out,          // in: x_proj (fp32); overwritten with h
             const float* __restrict__ Whh, const float* __restrict__ h0,
             unsigned* __restrict__ hexch)
{
    __shared__ short lds[2][16 * 1024];   // [chain][16 rows][1024], swizzled, 64 KiB

    const int tid  = threadIdx.x;
    const int pair = blockIdx.x >> 3;   // 0..3
    const int role = blockIdx.x & 7;    // 0..7
    const int lane = tid & 63;
    const int w    = tid >> 6;          // 0..7
    const int col  = lane & 15, quad = lane >> 4;
    const int nglob = role * 128 + w * 16 + col;
    const int b0   = quad * 4;          // valid batches only b0 < 8
    const int bsafe = b0 & 7;
    const int batA = pair * 16, batB = pair * 16 + 8;
    const int grpA = pair * 2, grpB = pair * 2 + 1;

    // zero MFMA rows 8..15 of both chains (A rows 8..15 = 0 -> C rows = 0)
    {
        unsigned* z0 = (unsigned*)(lds[0] + 8 * 1024);
        unsigned* z1 = (unsigned*)(lds[1] + 8 * 1024);
        for (int i = tid; i < 4096; i += 512) { z0[i] = 0u; z1[i] = 0u; }
    }

    // B-fragments: W_hh[n][k], k = kb*32 + quad*8 + j
    shortx8 bfrag[32];
    {
        const float* wrow = Whh + (size_t)nglob * HDIM + quad * 8;
#pragma unroll
        for (int kb = 0; kb < 32; kb++) {
            const floatx4* p = (const floatx4*)(wrow + kb * 32);
            bfrag[kb] = pack8(p[0], p[1]);
        }
    }

    // prologue: stage A(0), B(0) from h0 (swizzled); load xp(0)
    {
        const int cb = tid * 4;   // byte col (covers all 1024 shorts per row)
#pragma unroll
        for (int j = 0; j < 8; j++) {
            floatx2 fA = *(const floatx2*)(h0 + (size_t)(batA + j) * HDIM + tid * 2);
            floatx2 fB = *(const floatx2*)(h0 + (size_t)(batB + j) * HDIM + tid * 2);
            const unsigned pA = (unsigned)(unsigned short)f2bf(fA[0]) |
                                ((unsigned)(unsigned short)f2bf(fA[1]) << 16);
            const unsigned pB = (unsigned)(unsigned short)f2bf(fB[0]) |
                                ((unsigned)(unsigned short)f2bf(fB[1]) << 16);
            *(unsigned*)((char*)lds[0] + SWZ(j, cb)) = pA;
            *(unsigned*)((char*)lds[1] + SWZ(j, cb)) = pB;
        }
    }
    float xpA[4], xpB[4];
#pragma unroll
    for (int r = 0; r < 4; r++) {
        xpA[r] = out[(size_t)(batA + bsafe + r) * (TDIM * HDIM) + nglob];
        xpB[r] = out[(size_t)(batB + bsafe + r) * (TDIM * HDIM) + nglob];
    }
    __syncthreads();

    for (int t = 0; t < TDIM; ++t) {
        // P1: compute A(t); sync B(t) for P2 (skip at t=0: prestaged)
        phase(lds[0], lds[1], bfrag, xpA, out, hexch,
              t, (t == 0) ? -1 : t, batA, grpA, grpB,
              nglob, b0, bsafe, col, quad, w, lane);
        // P2: compute B(t); sync A(t+1) for next P1 (skip at the end)
        phase(lds[1], lds[0], bfrag, xpB, out, hexch,
              t, (t + 1 < TDIM) ? (t + 1) : -1, batB, grpB, grpA,
              nglob, b0, bsafe, col, quad, w, lane);
    }
}

// ---------------------------------------------------------------------------
extern "C" void kernel_launch(void* const* d_in, const int* in_sizes, int n_in,
                              void* d_out, int out_size, void* d_ws, size_t ws_size,
                              hipStream_t stream)
{
    const float* input = (const float*)d_in[0];
    const float* h0    = (const float*)d_in[1];
    const float* W_ih  = (const float*)d_in[2];
    const float* b_ih  = (const float*)d_in[3];
    const float* W_hh  = (const float*)d_in[4];
    const float* b_hh  = (const float*)d_in[5];
    float* out = (float*)d_out;

    unsigned* hexch = (unsigned*)d_ws;  // 2 slots x 8 groups x 8 rows x 1024 words = 512 KiB

    // stale tags must not alias this run's (tag 0 is never polled)
    hipMemsetAsync(hexch, 0, (size_t)2 * 65536 * 4, stream);

    xp_gemm<<<dim3(4096), dim3(256), 0, stream>>>(input, W_ih, b_ih, b_hh, out);
    rnn_rec<<<dim3(32),   dim3(512), 0, stream>>>(out, W_hh, h0, hexch);
}